// Round 11
// baseline (211.081 us; speedup 1.0000x reference)
//
#include <hip/hip_runtime.h>
#include <math.h>

#define O_ 3
#define P_ 128
#define G_ 64
#define N_ 20000
#define H_ 512
#define D_ 128
#define M_ (O_*P_)          // 384 anchors

static constexpr float TEMP_INV = 10.0f;   // 1/0.1
static constexpr float EPS_ = 1e-12f;

__device__ __forceinline__ unsigned short f2bf(float f) {   // round-to-nearest-even
    unsigned int u = __float_as_uint(f);
    unsigned int r = (u + 0x7FFFu + ((u >> 16) & 1u)) >> 16;
    return (unsigned short)r;
}
__device__ __forceinline__ float bf2f(unsigned short s) {
    return __uint_as_float((unsigned int)s << 16);
}

// ---------------------------------------------------------------------------
// K0: convert W1,W2 to bf16 in workspace (re-done per replay: d_ws is
// re-poisoned; d_in is read-only). 480 blocks x 512 thr, 1 float4 each:
// 196608 W1-quads + 49152 W2-quads = 245760 = 480*512 exactly.
// Also zeroes d_out (ordered before k_loss by two kernel boundaries).
// ---------------------------------------------------------------------------
__global__ __launch_bounds__(512) void k_cvt(const float* __restrict__ W1,
                                             const float* __restrict__ W2,
                                             unsigned short* __restrict__ W1b,
                                             unsigned short* __restrict__ W2b,
                                             float* __restrict__ out) {
    const int g = blockIdx.x * 512 + threadIdx.x;   // 0..245759
    if (g == 0) *out = 0.f;
    const float4* src;
    ushort4* dst;
    int i;
    if (g < 196608) { src = (const float4*)W1; dst = (ushort4*)W1b; i = g; }
    else            { src = (const float4*)W2; dst = (ushort4*)W2b; i = g - 196608; }
    const float4 v = src[i];
    ushort4 r;
    r.x = f2bf(v.x); r.y = f2bf(v.y); r.z = f2bf(v.z); r.w = f2bf(v.w);
    dst[i] = r;
}

// ---------------------------------------------------------------------------
// K1: fused per-(o,p) pipeline: gather+mean -> GEMM1+ReLU -> GEMM2 -> l2norm.
// 384 blocks x 512 threads. __launch_bounds__(512,4): VGPR cap 128 so the
// 16 gather loads can ALL be in flight (64 data VGPRs), still 2 blocks/CU.
// Weights read as bf16 (W1 192 MB, W2 48 MB of L2 traffic), f32 accumulate.
// ---------------------------------------------------------------------------
__global__ __launch_bounds__(512, 4) void k_fused(const float* __restrict__ emb,
                                                  const int* __restrict__ idx,
                                                  const unsigned short* __restrict__ W1b,
                                                  const float* __restrict__ b1,
                                                  const unsigned short* __restrict__ W2b,
                                                  const float* __restrict__ b2,
                                                  float* __restrict__ z) {
    const int b = blockIdx.x;            // o*128 + p
    const int o = b >> 7, p = b & 127;
    const int t = threadIdx.x;           // 0..511

    __shared__ int    sIdx[G_];          // 256 B
    __shared__ float  sP[H_];            // 2 KB   proto row
    __shared__ float  sH[H_];            // 2 KB   hidden row
    __shared__ float4 sPart[512];        // 8 KB   phase-shared scratch
    __shared__ float  sZ[D_];            // 512 B
    __shared__ float  sNr[2];

    // ---- phase 1: gather + mean -> sP ----
    // thread = (g-quarter q, float4 col c4). Explicit 16-element register
    // array: all 16 global loads issued before any add -> 16 outstanding.
    {
        const int q = t >> 7, c4 = t & 127;
        if (t < G_) sIdx[t] = idx[b * G_ + t];
        __syncthreads();

        const float* base = emb + (size_t)o * N_ * H_ + (size_t)c4 * 4;
        float4 v[16];
        #pragma unroll
        for (int g = 0; g < 16; ++g)
            v[g] = *(const float4*)(base + (size_t)((unsigned)sIdx[q * 16 + g]) * H_);

        float4 acc = make_float4(0.f, 0.f, 0.f, 0.f);
        #pragma unroll
        for (int g = 0; g < 16; ++g) {
            acc.x += v[g].x; acc.y += v[g].y; acc.z += v[g].z; acc.w += v[g].w;
        }
        sPart[q * 128 + c4] = acc;       // sPart as [4][128]
        __syncthreads();

        if (q == 0) {
            const float4 a0 = sPart[0 * 128 + c4], a1 = sPart[1 * 128 + c4];
            const float4 a2 = sPart[2 * 128 + c4], a3 = sPart[3 * 128 + c4];
            const float s = 1.0f / (float)G_;
            float4 r;
            r.x = (a0.x + a1.x + a2.x + a3.x) * s;
            r.y = (a0.y + a1.y + a2.y + a3.y) * s;
            r.z = (a0.z + a1.z + a2.z + a3.z) * s;
            r.w = (a0.w + a1.w + a2.w + a3.w) * s;
            ((float4*)sP)[c4] = r;
        }
    }
    __syncthreads();

    // ---- phase 2: h = relu(sP @ W1 + b1) -> sH ----
    // thread = (ks = t>>7: h-split 0..3, kq = t&127: col quad). bf16 W1:
    // ushort4 = 8 B/lane, wave reads 512 B contiguous per h.
    {
        const int ks = t >> 7, kq = t & 127;
        const unsigned short* w1 = W1b + (size_t)o * H_ * H_ + kq * 4;  // row h at w1 + h*512
        float4 acc = make_float4(0.f, 0.f, 0.f, 0.f);
        const int h0 = ks * 128;
        #pragma unroll 16
        for (int h = 0; h < 128; ++h) {
            const float a = sP[h0 + h];
            const ushort4 wv = *(const ushort4*)(w1 + (size_t)(h0 + h) * H_);
            acc.x = fmaf(a, bf2f(wv.x), acc.x);
            acc.y = fmaf(a, bf2f(wv.y), acc.y);
            acc.z = fmaf(a, bf2f(wv.z), acc.z);
            acc.w = fmaf(a, bf2f(wv.w), acc.w);
        }
        sPart[ks * 128 + kq] = acc;      // sPart as [4][128]
        __syncthreads();

        if (ks == 0) {                   // t < 128
            const float4 r0 = sPart[0 * 128 + kq], r1 = sPart[1 * 128 + kq];
            const float4 r2 = sPart[2 * 128 + kq], r3 = sPart[3 * 128 + kq];
            const float4 bb = ((const float4*)(b1 + (size_t)o * H_))[kq];
            float4 r;
            r.x = fmaxf(r0.x + r1.x + r2.x + r3.x + bb.x, 0.f);
            r.y = fmaxf(r0.y + r1.y + r2.y + r3.y + bb.y, 0.f);
            r.z = fmaxf(r0.z + r1.z + r2.z + r3.z + bb.z, 0.f);
            r.w = fmaxf(r0.w + r1.w + r2.w + r3.w + bb.w, 0.f);
            ((float4*)sH)[kq] = r;
        }
    }
    __syncthreads();

    // ---- phase 3: z-row = l2norm(sH @ W2 + b2), anchor m = p*3 + o ----
    // thread = (ks16 = t>>5: h-split 0..15, dq = t&31: col quad). bf16 W2.
    {
        const int ks16 = t >> 5, dq = t & 31;
        const unsigned short* w2 = W2b + (size_t)o * H_ * D_ + dq * 4;  // row h at w2 + h*128
        float4 acc = make_float4(0.f, 0.f, 0.f, 0.f);
        const int h0 = ks16 * 32;
        #pragma unroll 8
        for (int h = 0; h < 32; ++h) {
            const float a = sH[h0 + h];
            const ushort4 wv = *(const ushort4*)(w2 + (size_t)(h0 + h) * D_);
            acc.x = fmaf(a, bf2f(wv.x), acc.x);
            acc.y = fmaf(a, bf2f(wv.y), acc.y);
            acc.z = fmaf(a, bf2f(wv.z), acc.z);
            acc.w = fmaf(a, bf2f(wv.w), acc.w);
        }
        sPart[ks16 * 32 + dq] = acc;     // sPart as [16][32]
        __syncthreads();

        if (t < 32) {
            float4 s = make_float4(0.f, 0.f, 0.f, 0.f);
            #pragma unroll
            for (int j = 0; j < 16; ++j) {
                const float4 v = sPart[j * 32 + t];
                s.x += v.x; s.y += v.y; s.z += v.z; s.w += v.w;
            }
            const float4 bb = ((const float4*)(b2 + (size_t)o * D_))[t];
            s.x += bb.x; s.y += bb.y; s.z += bb.z; s.w += bb.w;
            ((float4*)sZ)[t] = s;
        }
        __syncthreads();

        if (t < D_) {                    // waves 0-1, fully active
            const float v = sZ[t];
            float s = v * v;
            #pragma unroll
            for (int off = 32; off > 0; off >>= 1) s += __shfl_down(s, off, 64);
            if ((t & 63) == 0) sNr[t >> 6] = s;
        }
        __syncthreads();
        if (t < D_) {
            const float inv = 1.0f / (sqrtf(sNr[0] + sNr[1]) + EPS_);
            z[(size_t)(p * O_ + o) * D_ + t] = sZ[t] * inv;
        }
    }
}

// ---------------------------------------------------------------------------
// K2: supervised-contrastive loss. One block per anchor i (384 blocks, 256 thr
// = 4 waves). Thread t handles j = t, plus j = t+256 if t < 128.
// ---------------------------------------------------------------------------
__global__ __launch_bounds__(256) void k_loss(const float* __restrict__ z,
                                              float* __restrict__ out) {
    const int i = blockIdx.x;            // 0..383
    const int t = threadIdx.x;
    __shared__ float zi[D_];
    if (t < D_) zi[t] = z[(size_t)i * D_ + t];
    __syncthreads();
    const int pi = i / 3;                // pathway label of anchor
    float denom = 0.f, pos = 0.f;
    const float4* zi4 = (const float4*)zi;
    #pragma unroll
    for (int jj = 0; jj < 2; ++jj) {
        const int j = t + jj * 256;
        if (j < M_) {
            const float4* zj = (const float4*)(z + (size_t)j * D_);
            float dot = 0.f;
            #pragma unroll 8
            for (int q = 0; q < D_ / 4; ++q) {
                const float4 a = zi4[q];
                const float4 bb = zj[q];
                dot = fmaf(a.x, bb.x, fmaf(a.y, bb.y, fmaf(a.z, bb.z, fmaf(a.w, bb.w, dot))));
            }
            if (j != i) {
                const float e = __expf(dot * TEMP_INV);
                denom += e;
                if (j / 3 == pi) pos += e;
            }
        }
    }
    #pragma unroll
    for (int off = 32; off > 0; off >>= 1) {
        denom += __shfl_down(denom, off, 64);
        pos   += __shfl_down(pos,   off, 64);
    }
    __shared__ float rd[4], rp[4];
    const int lane = t & 63, wid = t >> 6;
    if (lane == 0) { rd[wid] = denom; rp[wid] = pos; }
    __syncthreads();
    if (t == 0) {
        const float dn = rd[0] + rd[1] + rd[2] + rd[3] + EPS_;
        const float ps = rp[0] + rp[1] + rp[2] + rp[3] + EPS_;
        const float loss_i = logf(dn) - logf(ps);   // = -log(pos/denom)
        atomicAdd(out, loss_i * (1.0f / (float)M_));
    }
}

// ---------------------------------------------------------------------------
extern "C" void kernel_launch(void* const* d_in, const int* in_sizes, int n_in,
                              void* d_out, int out_size, void* d_ws, size_t ws_size,
                              hipStream_t stream) {
    const float* emb = (const float*)d_in[0];   // [3,20000,512]
    const float* W1  = (const float*)d_in[1];   // [3,512,512]
    const float* b1  = (const float*)d_in[2];   // [3,512]
    const float* W2  = (const float*)d_in[3];   // [3,512,128]
    const float* b2  = (const float*)d_in[4];   // [3,128]
    const int*   idx = (const int*)d_in[5];     // [3,128,64]

    float* ws   = (float*)d_ws;
    float* zbuf = ws;                            // 384*128 floats
    unsigned short* W1b = (unsigned short*)(ws + 49152);            // 786432 bf16
    unsigned short* W2b = (unsigned short*)(ws + 49152 + 393216);   // 196608 bf16

    // d_out zeroed inside k_cvt (2 kernel boundaries before k_loss's atomics).
    k_cvt  <<<dim3(480), dim3(512), 0, stream>>>(W1, W2, W1b, W2b, (float*)d_out);
    k_fused<<<dim3(M_),  dim3(512), 0, stream>>>(emb, idx, W1b, b1, W2b, b2, zbuf);
    k_loss <<<dim3(M_),  dim3(256), 0, stream>>>(zbuf, (float*)d_out);
}

// Round 12
// 207.229 us; speedup vs baseline: 1.0186x; 1.0186x over previous
//
#include <hip/hip_runtime.h>
#include <math.h>

#define O_ 3
#define P_ 128
#define G_ 64
#define N_ 20000
#define H_ 512
#define D_ 128
#define M_ (O_*P_)          // 384 anchors

static constexpr float TEMP_INV = 10.0f;   // 1/0.1
static constexpr float EPS_ = 1e-12f;

__device__ __forceinline__ unsigned short f2bf(float f) {   // round-to-nearest-even
    unsigned int u = __float_as_uint(f);
    unsigned int r = (u + 0x7FFFu + ((u >> 16) & 1u)) >> 16;
    return (unsigned short)r;
}
__device__ __forceinline__ float bf2f(unsigned short s) {
    return __uint_as_float((unsigned int)s << 16);
}

// ---------------------------------------------------------------------------
// K0: convert W1,W2 to bf16 in workspace (re-done per replay: d_ws is
// re-poisoned; d_in is read-only). 480 blocks x 512 thr, 1 float4 each:
// 196608 W1-quads + 49152 W2-quads = 245760 = 480*512 exactly.
// Also zeroes d_out (ordered before k_loss by two kernel boundaries).
// ---------------------------------------------------------------------------
__global__ __launch_bounds__(512) void k_cvt(const float* __restrict__ W1,
                                             const float* __restrict__ W2,
                                             unsigned short* __restrict__ W1b,
                                             unsigned short* __restrict__ W2b,
                                             float* __restrict__ out) {
    const int g = blockIdx.x * 512 + threadIdx.x;   // 0..245759
    if (g == 0) *out = 0.f;
    const float4* src;
    ushort4* dst;
    int i;
    if (g < 196608) { src = (const float4*)W1; dst = (ushort4*)W1b; i = g; }
    else            { src = (const float4*)W2; dst = (ushort4*)W2b; i = g - 196608; }
    const float4 v = src[i];
    ushort4 r;
    r.x = f2bf(v.x); r.y = f2bf(v.y); r.z = f2bf(v.z); r.w = f2bf(v.w);
    dst[i] = r;
}

// ---------------------------------------------------------------------------
// K1: fused per-(o,p) pipeline: gather+mean -> GEMM1+ReLU -> GEMM2 -> l2norm.
// 384 blocks x 512 threads = 12 waves/CU (grid-limited occupancy — do not
// touch VGPR bounds, R11 measured a regression). Weights read as bf16
// (W1 192 MB, W2 48 MB of L2 traffic), f32 accumulate. Mappings = R9/R10.
// ---------------------------------------------------------------------------
__global__ __launch_bounds__(512) void k_fused(const float* __restrict__ emb,
                                               const int* __restrict__ idx,
                                               const unsigned short* __restrict__ W1b,
                                               const float* __restrict__ b1,
                                               const unsigned short* __restrict__ W2b,
                                               const float* __restrict__ b2,
                                               float* __restrict__ z) {
    const int b = blockIdx.x;            // o*128 + p
    const int o = b >> 7, p = b & 127;
    const int t = threadIdx.x;           // 0..511

    __shared__ int    sIdx[G_];          // 256 B
    __shared__ float  sP[H_];            // 2 KB   proto row
    __shared__ float  sH[H_];            // 2 KB   hidden row
    __shared__ float4 sPart[512];        // 8 KB   phase-shared scratch
    __shared__ float  sZ[D_];            // 512 B
    __shared__ float  sNr[2];

    // ---- phase 1: gather + mean -> sP ----
    // thread = (g-quarter q, float4 col c4); 16 independent 16B loads/lane
    // (R2-measured: ~192 KB in flight per CU >> 9 KB needed -> BW-saturated).
    {
        const int q = t >> 7, c4 = t & 127;
        if (t < G_) sIdx[t] = idx[b * G_ + t];
        __syncthreads();

        const float* base = emb + (size_t)o * N_ * H_ + (size_t)c4 * 4;
        float4 acc = make_float4(0.f, 0.f, 0.f, 0.f);
        #pragma unroll
        for (int g = 0; g < 16; ++g) {
            const float4 v = *(const float4*)(base + (size_t)((unsigned)sIdx[q * 16 + g]) * H_);
            acc.x += v.x; acc.y += v.y; acc.z += v.z; acc.w += v.w;
        }
        sPart[q * 128 + c4] = acc;       // sPart as [4][128]
        __syncthreads();

        if (q == 0) {
            const float4 a0 = sPart[0 * 128 + c4], a1 = sPart[1 * 128 + c4];
            const float4 a2 = sPart[2 * 128 + c4], a3 = sPart[3 * 128 + c4];
            const float s = 1.0f / (float)G_;
            float4 r;
            r.x = (a0.x + a1.x + a2.x + a3.x) * s;
            r.y = (a0.y + a1.y + a2.y + a3.y) * s;
            r.z = (a0.z + a1.z + a2.z + a3.z) * s;
            r.w = (a0.w + a1.w + a2.w + a3.w) * s;
            ((float4*)sP)[c4] = r;
        }
    }
    __syncthreads();

    // ---- phase 2: h = relu(sP @ W1 + b1) -> sH ----
    // thread = (ks = t>>7: h-split 0..3, kq = t&127: col quad). bf16 W1:
    // ushort4 = 8 B/lane, wave reads 512 B contiguous per h.
    {
        const int ks = t >> 7, kq = t & 127;
        const unsigned short* w1 = W1b + (size_t)o * H_ * H_ + kq * 4;  // row h at w1 + h*512
        float4 acc = make_float4(0.f, 0.f, 0.f, 0.f);
        const int h0 = ks * 128;
        #pragma unroll 16
        for (int h = 0; h < 128; ++h) {
            const float a = sP[h0 + h];
            const ushort4 wv = *(const ushort4*)(w1 + (size_t)(h0 + h) * H_);
            acc.x = fmaf(a, bf2f(wv.x), acc.x);
            acc.y = fmaf(a, bf2f(wv.y), acc.y);
            acc.z = fmaf(a, bf2f(wv.z), acc.z);
            acc.w = fmaf(a, bf2f(wv.w), acc.w);
        }
        sPart[ks * 128 + kq] = acc;      // sPart as [4][128]
        __syncthreads();

        if (ks == 0) {                   // t < 128
            const float4 r0 = sPart[0 * 128 + kq], r1 = sPart[1 * 128 + kq];
            const float4 r2 = sPart[2 * 128 + kq], r3 = sPart[3 * 128 + kq];
            const float4 bb = ((const float4*)(b1 + (size_t)o * H_))[kq];
            float4 r;
            r.x = fmaxf(r0.x + r1.x + r2.x + r3.x + bb.x, 0.f);
            r.y = fmaxf(r0.y + r1.y + r2.y + r3.y + bb.y, 0.f);
            r.z = fmaxf(r0.z + r1.z + r2.z + r3.z + bb.z, 0.f);
            r.w = fmaxf(r0.w + r1.w + r2.w + r3.w + bb.w, 0.f);
            ((float4*)sH)[kq] = r;
        }
    }
    __syncthreads();

    // ---- phase 3: z-row = l2norm(sH @ W2 + b2), anchor m = p*3 + o ----
    // thread = (ks16 = t>>5: h-split 0..15, dq = t&31: col quad). bf16 W2.
    {
        const int ks16 = t >> 5, dq = t & 31;
        const unsigned short* w2 = W2b + (size_t)o * H_ * D_ + dq * 4;  // row h at w2 + h*128
        float4 acc = make_float4(0.f, 0.f, 0.f, 0.f);
        const int h0 = ks16 * 32;
        #pragma unroll 8
        for (int h = 0; h < 32; ++h) {
            const float a = sH[h0 + h];
            const ushort4 wv = *(const ushort4*)(w2 + (size_t)(h0 + h) * D_);
            acc.x = fmaf(a, bf2f(wv.x), acc.x);
            acc.y = fmaf(a, bf2f(wv.y), acc.y);
            acc.z = fmaf(a, bf2f(wv.z), acc.z);
            acc.w = fmaf(a, bf2f(wv.w), acc.w);
        }
        sPart[ks16 * 32 + dq] = acc;     // sPart as [16][32]
        __syncthreads();

        if (t < 32) {
            float4 s = make_float4(0.f, 0.f, 0.f, 0.f);
            #pragma unroll
            for (int j = 0; j < 16; ++j) {
                const float4 v = sPart[j * 32 + t];
                s.x += v.x; s.y += v.y; s.z += v.z; s.w += v.w;
            }
            const float4 bb = ((const float4*)(b2 + (size_t)o * D_))[t];
            s.x += bb.x; s.y += bb.y; s.z += bb.z; s.w += bb.w;
            ((float4*)sZ)[t] = s;
        }
        __syncthreads();

        if (t < D_) {                    // waves 0-1, fully active
            const float v = sZ[t];
            float s = v * v;
            #pragma unroll
            for (int off = 32; off > 0; off >>= 1) s += __shfl_down(s, off, 64);
            if ((t & 63) == 0) sNr[t >> 6] = s;
        }
        __syncthreads();
        if (t < D_) {
            const float inv = 1.0f / (sqrtf(sNr[0] + sNr[1]) + EPS_);
            z[(size_t)(p * O_ + o) * D_ + t] = sZ[t] * inv;
        }
    }
}

// ---------------------------------------------------------------------------
// K2: supervised-contrastive loss. One block per anchor i (384 blocks, 256 thr
// = 4 waves). Thread t handles j = t, plus j = t+256 if t < 128.
// ---------------------------------------------------------------------------
__global__ __launch_bounds__(256) void k_loss(const float* __restrict__ z,
                                              float* __restrict__ out) {
    const int i = blockIdx.x;            // 0..383
    const int t = threadIdx.x;
    __shared__ float zi[D_];
    if (t < D_) zi[t] = z[(size_t)i * D_ + t];
    __syncthreads();
    const int pi = i / 3;                // pathway label of anchor
    float denom = 0.f, pos = 0.f;
    const float4* zi4 = (const float4*)zi;
    #pragma unroll
    for (int jj = 0; jj < 2; ++jj) {
        const int j = t + jj * 256;
        if (j < M_) {
            const float4* zj = (const float4*)(z + (size_t)j * D_);
            float dot = 0.f;
            #pragma unroll 8
            for (int q = 0; q < D_ / 4; ++q) {
                const float4 a = zi4[q];
                const float4 bb = zj[q];
                dot = fmaf(a.x, bb.x, fmaf(a.y, bb.y, fmaf(a.z, bb.z, fmaf(a.w, bb.w, dot))));
            }
            if (j != i) {
                const float e = __expf(dot * TEMP_INV);
                denom += e;
                if (j / 3 == pi) pos += e;
            }
        }
    }
    #pragma unroll
    for (int off = 32; off > 0; off >>= 1) {
        denom += __shfl_down(denom, off, 64);
        pos   += __shfl_down(pos,   off, 64);
    }
    __shared__ float rd[4], rp[4];
    const int lane = t & 63, wid = t >> 6;
    if (lane == 0) { rd[wid] = denom; rp[wid] = pos; }
    __syncthreads();
    if (t == 0) {
        const float dn = rd[0] + rd[1] + rd[2] + rd[3] + EPS_;
        const float ps = rp[0] + rp[1] + rp[2] + rp[3] + EPS_;
        const float loss_i = logf(dn) - logf(ps);   // = -log(pos/denom)
        atomicAdd(out, loss_i * (1.0f / (float)M_));
    }
}

// ---------------------------------------------------------------------------
extern "C" void kernel_launch(void* const* d_in, const int* in_sizes, int n_in,
                              void* d_out, int out_size, void* d_ws, size_t ws_size,
                              hipStream_t stream) {
    const float* emb = (const float*)d_in[0];   // [3,20000,512]
    const float* W1  = (const float*)d_in[1];   // [3,512,512]
    const float* b1  = (const float*)d_in[2];   // [3,512]
    const float* W2  = (const float*)d_in[3];   // [3,512,128]
    const float* b2  = (const float*)d_in[4];   // [3,128]
    const int*   idx = (const int*)d_in[5];     // [3,128,64]

    float* ws   = (float*)d_ws;
    float* zbuf = ws;                            // 384*128 floats
    unsigned short* W1b = (unsigned short*)(ws + 49152);            // 786432 bf16
    unsigned short* W2b = (unsigned short*)(ws + 49152 + 393216);   // 196608 bf16

    // d_out zeroed inside k_cvt (2 kernel boundaries before k_loss's atomics).
    k_cvt  <<<dim3(480), dim3(512), 0, stream>>>(W1, W2, W1b, W2b, (float*)d_out);
    k_fused<<<dim3(M_),  dim3(512), 0, stream>>>(emb, idx, W1b, b1, W2b, b2, zbuf);
    k_loss <<<dim3(M_),  dim3(256), 0, stream>>>(zbuf, (float*)d_out);
}